// Round 1
// baseline (6232.429 us; speedup 1.0000x reference)
//
#include <hip/hip_runtime.h>
#include <math.h>

// Problem constants (B,C,H,W) = (32,256,128,128), downsample 0.5 -> (64,64)
#define NB 32
#define NC 256
#define NH 128
#define NW 128
#define NDH 64
#define NDW 64
#define NHW (NH * NW)          // 16384
#define NCELLS (NDH * NDW)     // 4096
#define OUT0_N (NB * NC * NCELLS)   // out: 33,554,432 floats
#define OUT1_BASE OUT0_N
#define OUT1_N (NB * 2 * NHW)       // offset: 1,048,576 floats
#define OUT2_BASE (OUT1_BASE + OUT1_N)  // destination: 134,217,728 floats

#define EPSF 1e-5f

// One block = 64 consecutive pixels (half a row) of one batch image.
// 256 threads: thread t owns channel sub-index ct=t>>4 (16 channels, stride 16)
// and pixel quad pg=(t&15)*4. Each thread loads 16 float4 of x (its 16 channels
// x its 4 pixels), keeps them in registers for the scatter phase.
__global__ __launch_bounds__(256) void k_main(
    const float* __restrict__ x, const float* __restrict__ cw,
    const float* __restrict__ cb, float* __restrict__ out,
    float* __restrict__ att_sum)
{
    __shared__ float cwS[3][NC];
    __shared__ float red[256][13];   // 13 = 12 partials + pad (bank-conflict)
    __shared__ float attv[64];
    __shared__ int   cellv[64];

    const int t    = threadIdx.x;
    const int blk  = blockIdx.x;
    const int b    = blk >> 8;         // 256 tiles per image
    const int tile = blk & 255;
    const int h    = tile >> 1;
    const int w0   = (tile & 1) << 6;  // 0 or 64
    const int pixbase = h * NW + w0;

    // conv_w is (3, C) row-major
    cwS[0][t] = cw[t];
    cwS[1][t] = cw[NC + t];
    cwS[2][t] = cw[2 * NC + t];
    __syncthreads();

    const int ct = t >> 4;            // 0..15
    const int pg = (t & 15) << 2;     // 0,4,...,60
    const float* xb = x + (size_t)b * NC * NHW + pixbase + pg;

    float4 xr[16];
    float p00 = 0, p01 = 0, p02 = 0;
    float p10 = 0, p11 = 0, p12 = 0;
    float p20 = 0, p21 = 0, p22 = 0;
    float p30 = 0, p31 = 0, p32 = 0;

    // Phase 1: streaming read of x (coalesced float4), partial dot over
    // this thread's 16 channels for its 4 pixels.
    #pragma unroll
    for (int i = 0; i < 16; ++i) {
        const int c = (i << 4) + ct;
        const float4 xv = *reinterpret_cast<const float4*>(xb + (size_t)c * NHW);
        xr[i] = xv;
        const float wc0 = cwS[0][c], wc1 = cwS[1][c], wc2 = cwS[2][c];
        p00 += xv.x * wc0; p01 += xv.x * wc1; p02 += xv.x * wc2;
        p10 += xv.y * wc0; p11 += xv.y * wc1; p12 += xv.y * wc2;
        p20 += xv.z * wc0; p21 += xv.z * wc1; p22 += xv.z * wc2;
        p30 += xv.w * wc0; p31 += xv.w * wc1; p32 += xv.w * wc2;
    }

    red[t][0]  = p00; red[t][1]  = p01; red[t][2]  = p02;
    red[t][3]  = p10; red[t][4]  = p11; red[t][5]  = p12;
    red[t][6]  = p20; red[t][7]  = p21; red[t][8]  = p22;
    red[t][9]  = p30; red[t][10] = p31; red[t][11] = p32;
    __syncthreads();

    // Cross-thread reduction: 16 partials per pixel (one per channel group).
    if (t < 64) {
        const int px  = t;
        const int row0 = px >> 2;          // which pixel-quad
        const int col  = (px & 3) * 3;     // slot within quad
        float s0 = 0, s1 = 0, s2 = 0;
        #pragma unroll
        for (int j = 0; j < 16; ++j) {
            const int r = row0 + (j << 4);
            s0 += red[r][col];
            s1 += red[r][col + 1];
            s2 += red[r][col + 2];
        }
        const float off0 = s0 + cb[0];
        const float off1 = s1 + cb[1];
        const float att  = expf(s2 + cb[2]);

        const float gy = (float)h * (1.0f / NH);
        const float gx = (float)(w0 + px) * (1.0f / NW);
        float dyf = fminf(fmaxf(gy + off0, 0.0f), 0.99999f);
        float dxf = fminf(fmaxf(gx + off1, 0.0f), 0.99999f);
        const int dy = (int)floorf(dyf * (float)NDH);
        const int dx = (int)floorf(dxf * (float)NDW);
        const int cell = dy * NDW + dx;

        atomicAdd(att_sum + b * NCELLS + cell, att);
        attv[px]  = att;
        cellv[px] = cell;

        // offset output (B,2,H,W)
        const int o1 = OUT1_BASE + b * 2 * NHW + pixbase + px;
        out[o1]       = off0;
        out[o1 + NHW] = off1;
    }
    __syncthreads();

    // Phase 2: scatter x*att into feat (= out[0:OUT0_N]) and write destination.
    const float a0 = attv[pg], a1 = attv[pg + 1], a2 = attv[pg + 2], a3 = attv[pg + 3];
    const int  c0 = cellv[pg], c1 = cellv[pg + 1], c2 = cellv[pg + 2], c3 = cellv[pg + 3];
    float* __restrict__ dst = out + OUT2_BASE;

    #pragma unroll
    for (int i = 0; i < 16; ++i) {
        const int c = (i << 4) + ct;
        const float4 xv = xr[i];
        const int basec = (b * NC + c) * NCELLS;   // < 2^25, fits int
        atomicAdd(out + (basec + c0), xv.x * a0);
        atomicAdd(out + (basec + c1), xv.y * a1);
        atomicAdd(out + (basec + c2), xv.z * a2);
        atomicAdd(out + (basec + c3), xv.w * a3);
        float4 dv;
        dv.x = (float)(basec + c0);
        dv.y = (float)(basec + c1);
        dv.z = (float)(basec + c2);
        dv.w = (float)(basec + c3);
        *reinterpret_cast<float4*>(dst + (size_t)(b * NC + c) * NHW + pixbase + pg) = dv;
    }
}

// out[i] = feat[i] / (att_sum[b,cell] + EPS), in place over out[0:OUT0_N]
__global__ __launch_bounds__(256) void k_div(
    float* __restrict__ out, const float* __restrict__ att_sum)
{
    const size_t i4 = ((size_t)blockIdx.x * 256 + threadIdx.x) * 4;
    float4 f = *reinterpret_cast<float4*>(out + i4);
    const int cell = (int)(i4 & (NCELLS - 1));
    const int b    = (int)(i4 >> 20);            // 256*4096 = 2^20 elems per batch
    const float4 s = *reinterpret_cast<const float4*>(att_sum + b * NCELLS + cell);
    f.x /= (s.x + EPSF);
    f.y /= (s.y + EPSF);
    f.z /= (s.z + EPSF);
    f.w /= (s.w + EPSF);
    *reinterpret_cast<float4*>(out + i4) = f;
}

extern "C" void kernel_launch(void* const* d_in, const int* in_sizes, int n_in,
                              void* d_out, int out_size, void* d_ws, size_t ws_size,
                              hipStream_t stream)
{
    (void)in_sizes; (void)n_in; (void)out_size; (void)ws_size;
    const float* x  = (const float*)d_in[0];
    const float* cw = (const float*)d_in[1];
    const float* cb = (const float*)d_in[2];
    float* out = (float*)d_out;
    float* att = (float*)d_ws;    // B*NCELLS floats = 512 KB scratch

    // feat accumulates directly into the `out` chunk; zero it + att_sum.
    hipMemsetAsync(out, 0, (size_t)OUT0_N * sizeof(float), stream);
    hipMemsetAsync(att, 0, (size_t)NB * NCELLS * sizeof(float), stream);

    k_main<<<dim3(NB * 256), dim3(256), 0, stream>>>(x, cw, cb, out, att);
    k_div<<<dim3(OUT0_N / 1024), dim3(256), 0, stream>>>(out, att);
}

// Round 2
// 1778.228 us; speedup vs baseline: 3.5049x; 3.5049x over previous
//
#include <hip/hip_runtime.h>
#include <math.h>

// Problem constants (B,C,H,W) = (32,256,128,128), downsample 0.5 -> (64,64)
#define NB 32
#define NC 256
#define NH 128
#define NW 128
#define NDH 64
#define NDW 64
#define NHW (NH * NW)          // 16384
#define NCELLS (NDH * NDW)     // 4096
#define OUT0_N (NB * NC * NCELLS)       // out: 33,554,432 floats
#define OUT1_BASE OUT0_N
#define OUT1_N (NB * 2 * NHW)           // offset: 1,048,576 floats
#define OUT2_BASE (OUT1_BASE + OUT1_N)  // destination: 134,217,728 floats

#define EPSF 1e-5f

typedef unsigned short u16;
typedef unsigned int   u32;

// ---- workspace layout (bytes), all 16B-aligned by construction ----
#define WS_CELLS   ((size_t)0)                       // u16 [NB*NHW]   1 MB
#define WS_ATTS    (WS_CELLS + (size_t)NB*NHW*2)     // f32 [NB*NHW]   2 MB
#define WS_STARTS  (WS_ATTS + (size_t)NB*NHW*4)      // i32 [NB*4097]  512 KB
#define WS_PIXS    (WS_STARTS + (size_t)NB*4097*4)   // u16 [NB*NHW]   1 MB
#define WS_CSRT    (WS_PIXS + (size_t)NB*NHW*2)      // u16 [NB*NHW]   1 MB
#define WS_ASRT    (WS_CSRT + (size_t)NB*NHW*2)      // f32 [NB*NHW]   2 MB
#define WS_ASUM    (WS_ASRT + (size_t)NB*NHW*4)      // f32 [NB*NCELLS] 512 KB
#define WS_NEED    (WS_ASUM + (size_t)NB*NCELLS*4)   // ~8.4 MB

// ============================================================================
// K1: conv (1x1, 3 outputs) -> offset output, destination output,
//     per-pixel cell id (u16) + attention (f32) into workspace.
// One block = 64 consecutive pixels (half a row) of one batch image.
// ============================================================================
__global__ __launch_bounds__(256) void k_conv(
    const float* __restrict__ x, const float* __restrict__ cw,
    const float* __restrict__ cb, float* __restrict__ out,
    u16* __restrict__ cells, float* __restrict__ atts)
{
    __shared__ float cwS[3][NC];
    __shared__ float red[256][13];
    __shared__ int   cellv[64];

    const int t    = threadIdx.x;
    const int blk  = blockIdx.x;
    const int b    = blk >> 8;
    const int tile = blk & 255;
    const int h    = tile >> 1;
    const int w0   = (tile & 1) << 6;
    const int pixbase = h * NW + w0;

    cwS[0][t] = cw[t];
    cwS[1][t] = cw[NC + t];
    cwS[2][t] = cw[2 * NC + t];
    __syncthreads();

    const int ct = t >> 4;            // channel group 0..15
    const int pg = (t & 15) << 2;     // pixel quad base 0..60
    const float* xb = x + (size_t)b * NC * NHW + pixbase + pg;

    float p00 = 0, p01 = 0, p02 = 0;
    float p10 = 0, p11 = 0, p12 = 0;
    float p20 = 0, p21 = 0, p22 = 0;
    float p30 = 0, p31 = 0, p32 = 0;

    #pragma unroll
    for (int i = 0; i < 16; ++i) {
        const int c = (i << 4) + ct;
        const float4 xv = *reinterpret_cast<const float4*>(xb + (size_t)c * NHW);
        const float wc0 = cwS[0][c], wc1 = cwS[1][c], wc2 = cwS[2][c];
        p00 += xv.x * wc0; p01 += xv.x * wc1; p02 += xv.x * wc2;
        p10 += xv.y * wc0; p11 += xv.y * wc1; p12 += xv.y * wc2;
        p20 += xv.z * wc0; p21 += xv.z * wc1; p22 += xv.z * wc2;
        p30 += xv.w * wc0; p31 += xv.w * wc1; p32 += xv.w * wc2;
    }

    red[t][0]  = p00; red[t][1]  = p01; red[t][2]  = p02;
    red[t][3]  = p10; red[t][4]  = p11; red[t][5]  = p12;
    red[t][6]  = p20; red[t][7]  = p21; red[t][8]  = p22;
    red[t][9]  = p30; red[t][10] = p31; red[t][11] = p32;
    __syncthreads();

    if (t < 64) {
        const int px   = t;
        const int row0 = px >> 2;
        const int col  = (px & 3) * 3;
        float s0 = 0, s1 = 0, s2 = 0;
        #pragma unroll
        for (int j = 0; j < 16; ++j) {
            const int r = row0 + (j << 4);
            s0 += red[r][col];
            s1 += red[r][col + 1];
            s2 += red[r][col + 2];
        }
        const float off0 = s0 + cb[0];
        const float off1 = s1 + cb[1];
        const float att  = expf(s2 + cb[2]);

        const float gy = (float)h * (1.0f / NH);
        const float gx = (float)(w0 + px) * (1.0f / NW);
        const float dyf = fminf(fmaxf(gy + off0, 0.0f), 0.99999f);
        const float dxf = fminf(fmaxf(gx + off1, 0.0f), 0.99999f);
        const int dy = (int)floorf(dyf * (float)NDH);
        const int dx = (int)floorf(dxf * (float)NDW);
        const int cell = dy * NDW + dx;

        cellv[px] = cell;
        cells[b * NHW + pixbase + px] = (u16)cell;
        atts [b * NHW + pixbase + px] = att;

        const int o1 = OUT1_BASE + b * 2 * NHW + pixbase + px;
        out[o1]       = off0;
        out[o1 + NHW] = off1;
    }
    __syncthreads();

    // destination output: dest[b,c,pix] = (b*C+c)*NCELLS + cell[pix]
    const int  c0 = cellv[pg], c1 = cellv[pg + 1], c2 = cellv[pg + 2], c3 = cellv[pg + 3];
    float* __restrict__ dst = out + OUT2_BASE;
    #pragma unroll
    for (int i = 0; i < 16; ++i) {
        const int c = (i << 4) + ct;
        const int basec = (b * NC + c) * NCELLS;
        float4 dv;
        dv.x = (float)(basec + c0);
        dv.y = (float)(basec + c1);
        dv.z = (float)(basec + c2);
        dv.w = (float)(basec + c3);
        *reinterpret_cast<float4*>(dst + (size_t)(b * NC + c) * NHW + pixbase + pg) = dv;
    }
}

// ============================================================================
// K2: per-batch counting sort of pixels by cell. One block per b.
// Emits: starts[4097], pix_sorted u16, cell_sorted u16, att_sorted f32,
//        att_sum f32[4096].
// ============================================================================
__global__ __launch_bounds__(1024) void k_sort(
    const u16* __restrict__ cells, const float* __restrict__ atts,
    int* __restrict__ starts, u16* __restrict__ pixs, u16* __restrict__ csrt,
    float* __restrict__ asrt, float* __restrict__ asum)
{
    __shared__ u32   hist[NCELLS];
    __shared__ float as_[NCELLS];
    __shared__ u32   ts[1024];

    const int t = threadIdx.x;
    const int b = blockIdx.x;
    const u16*   cb_ = cells + b * NHW;
    const float* ab_ = atts + b * NHW;

    #pragma unroll
    for (int j = 0; j < 4; ++j) { hist[t + 1024 * j] = 0u; as_[t + 1024 * j] = 0.f; }
    __syncthreads();

    #pragma unroll
    for (int j = 0; j < 16; ++j) {
        const int p  = t + 1024 * j;
        const int cl = cb_[p];
        atomicAdd(&hist[cl], 1u);
        atomicAdd(&as_[cl], ab_[p]);
    }
    __syncthreads();

    // exclusive scan of hist[4096] (4 per thread + Hillis-Steele over 1024)
    const u32 h0 = hist[4 * t], h1 = hist[4 * t + 1], h2 = hist[4 * t + 2], h3 = hist[4 * t + 3];
    const u32 T  = h0 + h1 + h2 + h3;
    ts[t] = T;
    __syncthreads();
    for (int off = 1; off < 1024; off <<= 1) {
        const u32 v = (t >= off) ? ts[t - off] : 0u;
        __syncthreads();
        ts[t] += v;
        __syncthreads();
    }
    const u32 base = ts[t] - T;   // exclusive prefix
    hist[4 * t]     = base;
    hist[4 * t + 1] = base + h0;
    hist[4 * t + 2] = base + h0 + h1;
    hist[4 * t + 3] = base + h0 + h1 + h2;

    int* sb = starts + b * 4097;
    sb[4 * t]     = (int)hist[4 * t];
    sb[4 * t + 1] = (int)hist[4 * t + 1];
    sb[4 * t + 2] = (int)hist[4 * t + 2];
    sb[4 * t + 3] = (int)hist[4 * t + 3];
    if (t == 0) sb[4096] = NHW;

    #pragma unroll
    for (int j = 0; j < 4; ++j)
        asum[b * NCELLS + t + 1024 * j] = as_[t + 1024 * j];
    __syncthreads();

    // scatter into sorted order (hist doubles as cursor array)
    #pragma unroll
    for (int j = 0; j < 16; ++j) {
        const int p  = t + 1024 * j;
        const int cl = cb_[p];
        const u32 pos = atomicAdd(&hist[cl], 1u);
        pixs[b * NHW + pos] = (u16)p;
        csrt[b * NHW + pos] = (u16)cl;
        asrt[b * NHW + pos] = ab_[p];
    }
}

// ============================================================================
// K3: gather. One block per (b,c). x-plane (64 KB) staged in LDS; each thread
// consumes 64 consecutive sorted entries (balanced), run-length-accumulates,
// flushes runs via LDS atomics, writes out = acc/(att_sum+EPS) coalesced.
// ============================================================================
__global__ __launch_bounds__(256) void k_gather(
    const float* __restrict__ x, const u16* __restrict__ pixs,
    const u16* __restrict__ csrt, const float* __restrict__ asrt,
    const float* __restrict__ asum, float* __restrict__ out)
{
    __shared__ float xpl[NHW];     // 64 KB
    __shared__ float acc[NCELLS];  // 16 KB

    const int t   = threadIdx.x;
    const int blk = blockIdx.x;
    const int b   = blk >> 8;
    const int c   = blk & 255;

    const float4* xp4  = reinterpret_cast<const float4*>(x + (size_t)(b * NC + c) * NHW);
    float4*       xpl4 = reinterpret_cast<float4*>(xpl);
    #pragma unroll
    for (int k = 0; k < 16; ++k) xpl4[t + 256 * k] = xp4[t + 256 * k];
    #pragma unroll
    for (int k = 0; k < 16; ++k) acc[t + 256 * k] = 0.f;
    __syncthreads();

    const int eb = b * NHW + t * 64;
    const u16*   pe = pixs + eb;
    const u16*   ce = csrt + eb;
    const float* ae = asrt + eb;

    float s  = 0.f;
    int   cur = ce[0];
    for (int i = 0; i < 64; ++i) {
        const int   cl = ce[i];
        const float v  = xpl[pe[i]] * ae[i];
        if (cl != cur) { atomicAdd(&acc[cur], s); cur = cl; s = v; }
        else           { s += v; }
    }
    atomicAdd(&acc[cur], s);
    __syncthreads();

    const float* as_ = asum + b * NCELLS;
    float* ob = out + (size_t)(b * NC + c) * NCELLS;
    #pragma unroll
    for (int k = 0; k < 16; ++k) {
        const int cl = t + 256 * k;
        ob[cl] = acc[cl] / (as_[cl] + EPSF);
    }
}

// ============================================================================
// Fallback path (round-1 kernel): used only if ws_size < WS_NEED.
// ============================================================================
__global__ __launch_bounds__(256) void k_fb_main(
    const float* __restrict__ x, const float* __restrict__ cw,
    const float* __restrict__ cb, float* __restrict__ out,
    float* __restrict__ att_sum)
{
    __shared__ float cwS[3][NC];
    __shared__ float red[256][13];
    __shared__ float attv[64];
    __shared__ int   cellv[64];

    const int t    = threadIdx.x;
    const int blk  = blockIdx.x;
    const int b    = blk >> 8;
    const int tile = blk & 255;
    const int h    = tile >> 1;
    const int w0   = (tile & 1) << 6;
    const int pixbase = h * NW + w0;

    cwS[0][t] = cw[t];
    cwS[1][t] = cw[NC + t];
    cwS[2][t] = cw[2 * NC + t];
    __syncthreads();

    const int ct = t >> 4;
    const int pg = (t & 15) << 2;
    const float* xb = x + (size_t)b * NC * NHW + pixbase + pg;

    float4 xr[16];
    float p00 = 0, p01 = 0, p02 = 0;
    float p10 = 0, p11 = 0, p12 = 0;
    float p20 = 0, p21 = 0, p22 = 0;
    float p30 = 0, p31 = 0, p32 = 0;

    #pragma unroll
    for (int i = 0; i < 16; ++i) {
        const int c = (i << 4) + ct;
        const float4 xv = *reinterpret_cast<const float4*>(xb + (size_t)c * NHW);
        xr[i] = xv;
        const float wc0 = cwS[0][c], wc1 = cwS[1][c], wc2 = cwS[2][c];
        p00 += xv.x * wc0; p01 += xv.x * wc1; p02 += xv.x * wc2;
        p10 += xv.y * wc0; p11 += xv.y * wc1; p12 += xv.y * wc2;
        p20 += xv.z * wc0; p21 += xv.z * wc1; p22 += xv.z * wc2;
        p30 += xv.w * wc0; p31 += xv.w * wc1; p32 += xv.w * wc2;
    }

    red[t][0]  = p00; red[t][1]  = p01; red[t][2]  = p02;
    red[t][3]  = p10; red[t][4]  = p11; red[t][5]  = p12;
    red[t][6]  = p20; red[t][7]  = p21; red[t][8]  = p22;
    red[t][9]  = p30; red[t][10] = p31; red[t][11] = p32;
    __syncthreads();

    if (t < 64) {
        const int px   = t;
        const int row0 = px >> 2;
        const int col  = (px & 3) * 3;
        float s0 = 0, s1 = 0, s2 = 0;
        #pragma unroll
        for (int j = 0; j < 16; ++j) {
            const int r = row0 + (j << 4);
            s0 += red[r][col];
            s1 += red[r][col + 1];
            s2 += red[r][col + 2];
        }
        const float off0 = s0 + cb[0];
        const float off1 = s1 + cb[1];
        const float att  = expf(s2 + cb[2]);
        const float gy = (float)h * (1.0f / NH);
        const float gx = (float)(w0 + px) * (1.0f / NW);
        const float dyf = fminf(fmaxf(gy + off0, 0.0f), 0.99999f);
        const float dxf = fminf(fmaxf(gx + off1, 0.0f), 0.99999f);
        const int dy = (int)floorf(dyf * (float)NDH);
        const int dx = (int)floorf(dxf * (float)NDW);
        const int cell = dy * NDW + dx;
        atomicAdd(att_sum + b * NCELLS + cell, att);
        attv[px]  = att;
        cellv[px] = cell;
        const int o1 = OUT1_BASE + b * 2 * NHW + pixbase + px;
        out[o1]       = off0;
        out[o1 + NHW] = off1;
    }
    __syncthreads();

    const float a0 = attv[pg], a1 = attv[pg + 1], a2 = attv[pg + 2], a3 = attv[pg + 3];
    const int  c0 = cellv[pg], c1 = cellv[pg + 1], c2 = cellv[pg + 2], c3 = cellv[pg + 3];
    float* __restrict__ dst = out + OUT2_BASE;
    #pragma unroll
    for (int i = 0; i < 16; ++i) {
        const int c = (i << 4) + ct;
        const float4 xv = xr[i];
        const int basec = (b * NC + c) * NCELLS;
        atomicAdd(out + (basec + c0), xv.x * a0);
        atomicAdd(out + (basec + c1), xv.y * a1);
        atomicAdd(out + (basec + c2), xv.z * a2);
        atomicAdd(out + (basec + c3), xv.w * a3);
        float4 dv;
        dv.x = (float)(basec + c0);
        dv.y = (float)(basec + c1);
        dv.z = (float)(basec + c2);
        dv.w = (float)(basec + c3);
        *reinterpret_cast<float4*>(dst + (size_t)(b * NC + c) * NHW + pixbase + pg) = dv;
    }
}

__global__ __launch_bounds__(256) void k_fb_div(
    float* __restrict__ out, const float* __restrict__ att_sum)
{
    const size_t i4 = ((size_t)blockIdx.x * 256 + threadIdx.x) * 4;
    float4 f = *reinterpret_cast<float4*>(out + i4);
    const int cell = (int)(i4 & (NCELLS - 1));
    const int b    = (int)(i4 >> 20);
    const float4 s = *reinterpret_cast<const float4*>(att_sum + b * NCELLS + cell);
    f.x /= (s.x + EPSF);
    f.y /= (s.y + EPSF);
    f.z /= (s.z + EPSF);
    f.w /= (s.w + EPSF);
    *reinterpret_cast<float4*>(out + i4) = f;
}

extern "C" void kernel_launch(void* const* d_in, const int* in_sizes, int n_in,
                              void* d_out, int out_size, void* d_ws, size_t ws_size,
                              hipStream_t stream)
{
    (void)in_sizes; (void)n_in; (void)out_size;
    const float* x  = (const float*)d_in[0];
    const float* cw = (const float*)d_in[1];
    const float* cb = (const float*)d_in[2];
    float* out = (float*)d_out;
    char*  ws  = (char*)d_ws;

    if (ws_size >= WS_NEED) {
        u16*   cells = (u16*)  (ws + WS_CELLS);
        float* atts  = (float*)(ws + WS_ATTS);
        int*   strt  = (int*)  (ws + WS_STARTS);
        u16*   pixs  = (u16*)  (ws + WS_PIXS);
        u16*   csrt  = (u16*)  (ws + WS_CSRT);
        float* asrt  = (float*)(ws + WS_ASRT);
        float* asum  = (float*)(ws + WS_ASUM);

        k_conv  <<<dim3(NB * 256), dim3(256),  0, stream>>>(x, cw, cb, out, cells, atts);
        k_sort  <<<dim3(NB),       dim3(1024), 0, stream>>>(cells, atts, strt, pixs, csrt, asrt, asum);
        k_gather<<<dim3(NB * NC),  dim3(256),  0, stream>>>(x, pixs, csrt, asrt, asum, out);
    } else {
        float* att = (float*)d_ws;  // B*NCELLS floats = 512 KB
        hipMemsetAsync(out, 0, (size_t)OUT0_N * sizeof(float), stream);
        hipMemsetAsync(att, 0, (size_t)NB * NCELLS * sizeof(float), stream);
        k_fb_main<<<dim3(NB * 256), dim3(256), 0, stream>>>(x, cw, cb, out, att);
        k_fb_div <<<dim3(OUT0_N / 1024), dim3(256), 0, stream>>>(out, att);
    }
}

// Round 3
// 463.691 us; speedup vs baseline: 13.4409x; 3.8349x over previous
//
#include <hip/hip_runtime.h>
#include <math.h>

// Problem constants (B,C,H,W) = (32,256,128,128), downsample 0.5 -> (64,64)
#define NB 32
#define NC 256
#define NH 128
#define NW 128
#define NDH 64
#define NDW 64
#define NHW (NH * NW)          // 16384
#define NCELLS (NDH * NDW)     // 4096
#define OUT0_N (NB * NC * NCELLS)       // out: 33,554,432 floats
#define OUT1_BASE OUT0_N
#define OUT1_N (NB * 2 * NHW)           // offset: 1,048,576 floats
#define OUT2_BASE (OUT1_BASE + OUT1_N)  // destination: 134,217,728 floats

#define EPSF 1e-5f

typedef unsigned short u16;
typedef unsigned int   u32;

// ---- workspace layout (bytes), 16B-aligned by construction; total 5.5 MB ----
#define WS_CELLS   ((size_t)0)                       // u16 [NB*NHW]   1 MB
#define WS_ATTS    (WS_CELLS + (size_t)NB*NHW*2)     // f32 [NB*NHW]   2 MB
#define WS_ECOMB   (WS_ATTS + (size_t)NB*NHW*4)      // u32 [NB*NHW]   2 MB  (cell<<16 | pix)
#define WS_ASUM    (WS_ECOMB + (size_t)NB*NHW*4)     // f32 [NB*NCELLS] 512 KB

// ============================================================================
// K1: 1x1 conv (3 outs) -> offset output, destination output,
//     per-pixel cell id (u16) + attention (f32) into workspace.
// One block = 64 consecutive pixels (half a row) of one batch image.
// ============================================================================
__global__ __launch_bounds__(256) void k_conv(
    const float* __restrict__ x, const float* __restrict__ cw,
    const float* __restrict__ cb, float* __restrict__ out,
    u16* __restrict__ cells, float* __restrict__ atts)
{
    __shared__ float cwS[3][NC];
    __shared__ float red[256][13];
    __shared__ int   cellv[64];

    const int t    = threadIdx.x;
    const int blk  = blockIdx.x;
    const int b    = blk >> 8;
    const int tile = blk & 255;
    const int h    = tile >> 1;
    const int w0   = (tile & 1) << 6;
    const int pixbase = h * NW + w0;

    cwS[0][t] = cw[t];
    cwS[1][t] = cw[NC + t];
    cwS[2][t] = cw[2 * NC + t];
    __syncthreads();

    const int ct = t >> 4;            // channel group 0..15
    const int pg = (t & 15) << 2;     // pixel quad base 0..60
    const float* xb = x + (size_t)b * NC * NHW + pixbase + pg;

    float p00 = 0, p01 = 0, p02 = 0;
    float p10 = 0, p11 = 0, p12 = 0;
    float p20 = 0, p21 = 0, p22 = 0;
    float p30 = 0, p31 = 0, p32 = 0;

    #pragma unroll
    for (int i = 0; i < 16; ++i) {
        const int c = (i << 4) + ct;
        const float4 xv = *reinterpret_cast<const float4*>(xb + (size_t)c * NHW);
        const float wc0 = cwS[0][c], wc1 = cwS[1][c], wc2 = cwS[2][c];
        p00 += xv.x * wc0; p01 += xv.x * wc1; p02 += xv.x * wc2;
        p10 += xv.y * wc0; p11 += xv.y * wc1; p12 += xv.y * wc2;
        p20 += xv.z * wc0; p21 += xv.z * wc1; p22 += xv.z * wc2;
        p30 += xv.w * wc0; p31 += xv.w * wc1; p32 += xv.w * wc2;
    }

    red[t][0]  = p00; red[t][1]  = p01; red[t][2]  = p02;
    red[t][3]  = p10; red[t][4]  = p11; red[t][5]  = p12;
    red[t][6]  = p20; red[t][7]  = p21; red[t][8]  = p22;
    red[t][9]  = p30; red[t][10] = p31; red[t][11] = p32;
    __syncthreads();

    if (t < 64) {
        const int px   = t;
        const int row0 = px >> 2;
        const int col  = (px & 3) * 3;
        float s0 = 0, s1 = 0, s2 = 0;
        #pragma unroll
        for (int j = 0; j < 16; ++j) {
            const int r = row0 + (j << 4);
            s0 += red[r][col];
            s1 += red[r][col + 1];
            s2 += red[r][col + 2];
        }
        const float off0 = s0 + cb[0];
        const float off1 = s1 + cb[1];
        const float att  = expf(s2 + cb[2]);

        const float gy = (float)h * (1.0f / NH);
        const float gx = (float)(w0 + px) * (1.0f / NW);
        const float dyf = fminf(fmaxf(gy + off0, 0.0f), 0.99999f);
        const float dxf = fminf(fmaxf(gx + off1, 0.0f), 0.99999f);
        const int dy = (int)floorf(dyf * (float)NDH);
        const int dx = (int)floorf(dxf * (float)NDW);
        const int cell = dy * NDW + dx;

        cellv[px] = cell;
        cells[b * NHW + pixbase + px] = (u16)cell;
        atts [b * NHW + pixbase + px] = att;

        const int o1 = OUT1_BASE + b * 2 * NHW + pixbase + px;
        out[o1]       = off0;
        out[o1 + NHW] = off1;
    }
    __syncthreads();

    // destination output: dest[b,c,pix] = (b*C+c)*NCELLS + cell[pix]
    const int  c0 = cellv[pg], c1 = cellv[pg + 1], c2 = cellv[pg + 2], c3 = cellv[pg + 3];
    float* __restrict__ dst = out + OUT2_BASE;
    #pragma unroll
    for (int i = 0; i < 16; ++i) {
        const int c = (i << 4) + ct;
        const int basec = (b * NC + c) * NCELLS;
        float4 dv;
        dv.x = (float)(basec + c0);
        dv.y = (float)(basec + c1);
        dv.z = (float)(basec + c2);
        dv.w = (float)(basec + c3);
        *reinterpret_cast<float4*>(dst + (size_t)(b * NC + c) * NHW + pixbase + pg) = dv;
    }
}

// ============================================================================
// K2: per-batch counting sort of pixels by cell. One block per b.
// Emits: ecomb u32[NHW] = (cell<<16)|pix in cell-sorted order, att_sum f32[4096].
// ============================================================================
__global__ __launch_bounds__(1024) void k_sort(
    const u16* __restrict__ cells, const float* __restrict__ atts,
    u32* __restrict__ ecomb, float* __restrict__ asum)
{
    __shared__ u32   hist[NCELLS];
    __shared__ float as_[NCELLS];
    __shared__ u32   ts[1024];

    const int t = threadIdx.x;
    const int b = blockIdx.x;
    const u16*   cb_ = cells + b * NHW;
    const float* ab_ = atts + b * NHW;

    #pragma unroll
    for (int j = 0; j < 4; ++j) { hist[t + 1024 * j] = 0u; as_[t + 1024 * j] = 0.f; }
    __syncthreads();

    #pragma unroll
    for (int j = 0; j < 16; ++j) {
        const int p  = t + 1024 * j;
        const int cl = cb_[p];
        atomicAdd(&hist[cl], 1u);
        atomicAdd(&as_[cl], ab_[p]);
    }
    __syncthreads();

    // exclusive scan of hist[4096] (4 per thread + Hillis-Steele over 1024)
    const u32 h0 = hist[4 * t], h1 = hist[4 * t + 1], h2 = hist[4 * t + 2], h3 = hist[4 * t + 3];
    const u32 T  = h0 + h1 + h2 + h3;
    ts[t] = T;
    __syncthreads();
    for (int off = 1; off < 1024; off <<= 1) {
        const u32 v = (t >= off) ? ts[t - off] : 0u;
        __syncthreads();
        ts[t] += v;
        __syncthreads();
    }
    const u32 base = ts[t] - T;   // exclusive prefix
    hist[4 * t]     = base;
    hist[4 * t + 1] = base + h0;
    hist[4 * t + 2] = base + h0 + h1;
    hist[4 * t + 3] = base + h0 + h1 + h2;

    #pragma unroll
    for (int j = 0; j < 4; ++j)
        asum[b * NCELLS + t + 1024 * j] = as_[t + 1024 * j];
    __syncthreads();

    // scatter into sorted order (hist doubles as cursor array)
    #pragma unroll
    for (int j = 0; j < 16; ++j) {
        const int p  = t + 1024 * j;
        const int cl = cb_[p];
        const u32 pos = atomicAdd(&hist[cl], 1u);
        ecomb[b * NHW + pos] = ((u32)cl << 16) | (u32)p;
    }
}

// ============================================================================
// K3: gather. One block per (b,c). Stage x-plane * att into LDS (64 KB),
// each thread consumes 64 consecutive sorted packed entries in 8-wide chunks:
// 2x uint4 entry loads -> 8 independent ds_read_b32 -> VALU run-length
// accumulate -> rare LDS atomic flush. Final coalesced normalized write.
// ============================================================================
__global__ __launch_bounds__(256) void k_gather(
    const float* __restrict__ x, const float* __restrict__ atts,
    const u32* __restrict__ ecomb, const float* __restrict__ asum,
    float* __restrict__ out)
{
    __shared__ float xpl[NHW];     // 64 KB  (x * att, premultiplied)
    __shared__ float acc[NCELLS];  // 16 KB

    const int t   = threadIdx.x;
    const int blk = blockIdx.x;
    const int b   = blk >> 8;
    const int c   = blk & 255;

    const float4* xp4  = reinterpret_cast<const float4*>(x + (size_t)(b * NC + c) * NHW);
    const float4* at4  = reinterpret_cast<const float4*>(atts + b * NHW);
    float4*       xpl4 = reinterpret_cast<float4*>(xpl);
    float4*       acc4 = reinterpret_cast<float4*>(acc);

    #pragma unroll
    for (int k = 0; k < 16; ++k) {
        float4 xv = xp4[t + 256 * k];
        const float4 av = at4[t + 256 * k];
        xv.x *= av.x; xv.y *= av.y; xv.z *= av.z; xv.w *= av.w;
        xpl4[t + 256 * k] = xv;
    }
    const float4 z4 = make_float4(0.f, 0.f, 0.f, 0.f);
    #pragma unroll
    for (int k = 0; k < 4; ++k) acc4[t + 256 * k] = z4;
    __syncthreads();

    const u32* el = ecomb + b * NHW + t * 64;   // 256B-aligned
    float s   = 0.f;
    int   cur = (int)(el[0] >> 16);

    #define ACCUM(E, V)                                            \
        {                                                          \
            const int cl_ = (int)((E) >> 16);                      \
            if (cl_ != cur) { atomicAdd(&acc[cur], s); s = 0.f; cur = cl_; } \
            s += (V);                                              \
        }

    for (int ch = 0; ch < 8; ++ch) {
        const uint4 e0 = *reinterpret_cast<const uint4*>(el + ch * 8);
        const uint4 e1 = *reinterpret_cast<const uint4*>(el + ch * 8 + 4);
        const float v0 = xpl[e0.x & 0xFFFFu];
        const float v1 = xpl[e0.y & 0xFFFFu];
        const float v2 = xpl[e0.z & 0xFFFFu];
        const float v3 = xpl[e0.w & 0xFFFFu];
        const float v4 = xpl[e1.x & 0xFFFFu];
        const float v5 = xpl[e1.y & 0xFFFFu];
        const float v6 = xpl[e1.z & 0xFFFFu];
        const float v7 = xpl[e1.w & 0xFFFFu];
        ACCUM(e0.x, v0); ACCUM(e0.y, v1); ACCUM(e0.z, v2); ACCUM(e0.w, v3);
        ACCUM(e1.x, v4); ACCUM(e1.y, v5); ACCUM(e1.z, v6); ACCUM(e1.w, v7);
    }
    atomicAdd(&acc[cur], s);
    #undef ACCUM
    __syncthreads();

    const float4* as4 = reinterpret_cast<const float4*>(asum + b * NCELLS);
    float4* ob4 = reinterpret_cast<float4*>(out + (size_t)(b * NC + c) * NCELLS);
    #pragma unroll
    for (int k = 0; k < 4; ++k) {
        float4 a = acc4[t + 256 * k];
        const float4 sv = as4[t + 256 * k];
        a.x /= (sv.x + EPSF);
        a.y /= (sv.y + EPSF);
        a.z /= (sv.z + EPSF);
        a.w /= (sv.w + EPSF);
        ob4[t + 256 * k] = a;
    }
}

extern "C" void kernel_launch(void* const* d_in, const int* in_sizes, int n_in,
                              void* d_out, int out_size, void* d_ws, size_t ws_size,
                              hipStream_t stream)
{
    (void)in_sizes; (void)n_in; (void)out_size; (void)ws_size;
    const float* x  = (const float*)d_in[0];
    const float* cw = (const float*)d_in[1];
    const float* cb = (const float*)d_in[2];
    float* out = (float*)d_out;
    char*  ws  = (char*)d_ws;

    u16*   cells = (u16*)  (ws + WS_CELLS);
    float* atts  = (float*)(ws + WS_ATTS);
    u32*   ecomb = (u32*)  (ws + WS_ECOMB);
    float* asum  = (float*)(ws + WS_ASUM);

    k_conv  <<<dim3(NB * 256), dim3(256),  0, stream>>>(x, cw, cb, out, cells, atts);
    k_sort  <<<dim3(NB),       dim3(1024), 0, stream>>>(cells, atts, ecomb, asum);
    k_gather<<<dim3(NB * NC),  dim3(256),  0, stream>>>(x, atts, ecomb, asum, out);
}

// Round 4
// 442.622 us; speedup vs baseline: 14.0807x; 1.0476x over previous
//
#include <hip/hip_runtime.h>
#include <math.h>

// Problem constants (B,C,H,W) = (32,256,128,128), downsample 0.5 -> (64,64)
#define NB 32
#define NC 256
#define NH 128
#define NW 128
#define NDH 64
#define NDW 64
#define NHW (NH * NW)          // 16384
#define NCELLS (NDH * NDW)     // 4096
#define OUT0_N (NB * NC * NCELLS)       // out: 33,554,432 floats
#define OUT1_BASE OUT0_N
#define OUT1_N (NB * 2 * NHW)           // offset: 1,048,576 floats
#define OUT2_BASE (OUT1_BASE + OUT1_N)  // destination: 134,217,728 floats

#define EPSF 1e-5f

typedef unsigned short u16;
typedef unsigned int   u32;

// ---- workspace layout (bytes), 16B-aligned by construction; total 5.5 MB ----
#define WS_CELLS   ((size_t)0)                       // u16 [NB*NHW]   1 MB
#define WS_ATTS    (WS_CELLS + (size_t)NB*NHW*2)     // f32 [NB*NHW]   2 MB
#define WS_ECOMB   (WS_ATTS + (size_t)NB*NHW*4)      // u32 [NB*NHW]   2 MB  (cell<<16 | pix)
#define WS_ASUM    (WS_ECOMB + (size_t)NB*NHW*4)     // f32 [NB*NCELLS] 512 KB

__device__ inline u16 f32_to_bf16_rn(float f) {
    const u32 u = __float_as_uint(f);
    return (u16)((u + 0x7FFFu + ((u >> 16) & 1u)) >> 16);
}

// ============================================================================
// K1: 1x1 conv (3 outs) -> offset output, destination output,
//     per-pixel cell id (u16) + attention (f32) into workspace.
// One block = 64 consecutive pixels (half a row) of one batch image.
// ============================================================================
__global__ __launch_bounds__(256) void k_conv(
    const float* __restrict__ x, const float* __restrict__ cw,
    const float* __restrict__ cb, float* __restrict__ out,
    u16* __restrict__ cells, float* __restrict__ atts)
{
    __shared__ float cwS[3][NC];
    __shared__ float red[256][13];
    __shared__ int   cellv[64];

    const int t    = threadIdx.x;
    const int blk  = blockIdx.x;
    const int b    = blk >> 8;
    const int tile = blk & 255;
    const int h    = tile >> 1;
    const int w0   = (tile & 1) << 6;
    const int pixbase = h * NW + w0;

    cwS[0][t] = cw[t];
    cwS[1][t] = cw[NC + t];
    cwS[2][t] = cw[2 * NC + t];
    __syncthreads();

    const int ct = t >> 4;            // channel group 0..15
    const int pg = (t & 15) << 2;     // pixel quad base 0..60
    const float* xb = x + (size_t)b * NC * NHW + pixbase + pg;

    float p00 = 0, p01 = 0, p02 = 0;
    float p10 = 0, p11 = 0, p12 = 0;
    float p20 = 0, p21 = 0, p22 = 0;
    float p30 = 0, p31 = 0, p32 = 0;

    #pragma unroll
    for (int i = 0; i < 16; ++i) {
        const int c = (i << 4) + ct;
        const float4 xv = *reinterpret_cast<const float4*>(xb + (size_t)c * NHW);
        const float wc0 = cwS[0][c], wc1 = cwS[1][c], wc2 = cwS[2][c];
        p00 += xv.x * wc0; p01 += xv.x * wc1; p02 += xv.x * wc2;
        p10 += xv.y * wc0; p11 += xv.y * wc1; p12 += xv.y * wc2;
        p20 += xv.z * wc0; p21 += xv.z * wc1; p22 += xv.z * wc2;
        p30 += xv.w * wc0; p31 += xv.w * wc1; p32 += xv.w * wc2;
    }

    red[t][0]  = p00; red[t][1]  = p01; red[t][2]  = p02;
    red[t][3]  = p10; red[t][4]  = p11; red[t][5]  = p12;
    red[t][6]  = p20; red[t][7]  = p21; red[t][8]  = p22;
    red[t][9]  = p30; red[t][10] = p31; red[t][11] = p32;
    __syncthreads();

    if (t < 64) {
        const int px   = t;
        const int row0 = px >> 2;
        const int col  = (px & 3) * 3;
        float s0 = 0, s1 = 0, s2 = 0;
        #pragma unroll
        for (int j = 0; j < 16; ++j) {
            const int r = row0 + (j << 4);
            s0 += red[r][col];
            s1 += red[r][col + 1];
            s2 += red[r][col + 2];
        }
        const float off0 = s0 + cb[0];
        const float off1 = s1 + cb[1];
        const float att  = expf(s2 + cb[2]);

        const float gy = (float)h * (1.0f / NH);
        const float gx = (float)(w0 + px) * (1.0f / NW);
        const float dyf = fminf(fmaxf(gy + off0, 0.0f), 0.99999f);
        const float dxf = fminf(fmaxf(gx + off1, 0.0f), 0.99999f);
        const int dy = (int)floorf(dyf * (float)NDH);
        const int dx = (int)floorf(dxf * (float)NDW);
        const int cell = dy * NDW + dx;

        cellv[px] = cell;
        cells[b * NHW + pixbase + px] = (u16)cell;
        atts [b * NHW + pixbase + px] = att;

        const int o1 = OUT1_BASE + b * 2 * NHW + pixbase + px;
        out[o1]       = off0;
        out[o1 + NHW] = off1;
    }
    __syncthreads();

    // destination output: dest[b,c,pix] = (b*C+c)*NCELLS + cell[pix]
    const int  c0 = cellv[pg], c1 = cellv[pg + 1], c2 = cellv[pg + 2], c3 = cellv[pg + 3];
    float* __restrict__ dst = out + OUT2_BASE;
    #pragma unroll
    for (int i = 0; i < 16; ++i) {
        const int c = (i << 4) + ct;
        const int basec = (b * NC + c) * NCELLS;
        float4 dv;
        dv.x = (float)(basec + c0);
        dv.y = (float)(basec + c1);
        dv.z = (float)(basec + c2);
        dv.w = (float)(basec + c3);
        *reinterpret_cast<float4*>(dst + (size_t)(b * NC + c) * NHW + pixbase + pg) = dv;
    }
}

// ============================================================================
// K2: per-batch counting sort of pixels by cell. One block per b.
// Emits: ecomb u32[NHW] = (cell<<16)|pix in cell-sorted order, att_sum f32[4096].
// ============================================================================
__global__ __launch_bounds__(1024) void k_sort(
    const u16* __restrict__ cells, const float* __restrict__ atts,
    u32* __restrict__ ecomb, float* __restrict__ asum)
{
    __shared__ u32   hist[NCELLS];
    __shared__ float as_[NCELLS];
    __shared__ u32   ts[1024];

    const int t = threadIdx.x;
    const int b = blockIdx.x;
    const u16*   cb_ = cells + b * NHW;
    const float* ab_ = atts + b * NHW;

    #pragma unroll
    for (int j = 0; j < 4; ++j) { hist[t + 1024 * j] = 0u; as_[t + 1024 * j] = 0.f; }
    __syncthreads();

    #pragma unroll
    for (int j = 0; j < 16; ++j) {
        const int p  = t + 1024 * j;
        const int cl = cb_[p];
        atomicAdd(&hist[cl], 1u);
        atomicAdd(&as_[cl], ab_[p]);
    }
    __syncthreads();

    // exclusive scan of hist[4096] (4 per thread + Hillis-Steele over 1024)
    const u32 h0 = hist[4 * t], h1 = hist[4 * t + 1], h2 = hist[4 * t + 2], h3 = hist[4 * t + 3];
    const u32 T  = h0 + h1 + h2 + h3;
    ts[t] = T;
    __syncthreads();
    for (int off = 1; off < 1024; off <<= 1) {
        const u32 v = (t >= off) ? ts[t - off] : 0u;
        __syncthreads();
        ts[t] += v;
        __syncthreads();
    }
    const u32 base = ts[t] - T;   // exclusive prefix
    hist[4 * t]     = base;
    hist[4 * t + 1] = base + h0;
    hist[4 * t + 2] = base + h0 + h1;
    hist[4 * t + 3] = base + h0 + h1 + h2;

    #pragma unroll
    for (int j = 0; j < 4; ++j)
        asum[b * NCELLS + t + 1024 * j] = as_[t + 1024 * j];
    __syncthreads();

    // scatter into sorted order (hist doubles as cursor array)
    #pragma unroll
    for (int j = 0; j < 16; ++j) {
        const int p  = t + 1024 * j;
        const int cl = cb_[p];
        const u32 pos = atomicAdd(&hist[cl], 1u);
        ecomb[b * NHW + pos] = ((u32)cl << 16) | (u32)p;
    }
}

// ============================================================================
// K3: gather. One block per (b,c). Stage bf16(x * att) into LDS (32 KB) +
// f32 acc (16 KB) => 48 KB/block => 3 blocks/CU so staging (HBM) of one block
// overlaps gathering (LDS pipe) of another. Each thread consumes 64
// consecutive sorted packed entries in 8-wide chunks: 2x uint4 entry loads ->
// 8 independent ds_read_u16 -> VALU run-length accumulate -> rare LDS atomic
// flush. Final coalesced normalized f32 write.
// ============================================================================
__global__ __launch_bounds__(256) void k_gather(
    const float* __restrict__ x, const float* __restrict__ atts,
    const u32* __restrict__ ecomb, const float* __restrict__ asum,
    float* __restrict__ out)
{
    __shared__ u16   xpl[NHW];     // 32 KB  (bf16(x * att))
    __shared__ float acc[NCELLS];  // 16 KB

    const int t   = threadIdx.x;
    const int blk = blockIdx.x;
    const int b   = blk >> 8;
    const int c   = blk & 255;

    const float4* xp4  = reinterpret_cast<const float4*>(x + (size_t)(b * NC + c) * NHW);
    const float4* at4  = reinterpret_cast<const float4*>(atts + b * NHW);
    float4*       acc4 = reinterpret_cast<float4*>(acc);

    #pragma unroll
    for (int k = 0; k < 16; ++k) {
        const int idx = t + 256 * k;         // covers pixels idx*4 .. idx*4+3
        const float4 xv = xp4[idx];
        const float4 av = at4[idx];
        const u32 lo = (u32)f32_to_bf16_rn(xv.x * av.x)
                     | ((u32)f32_to_bf16_rn(xv.y * av.y) << 16);
        const u32 hi = (u32)f32_to_bf16_rn(xv.z * av.z)
                     | ((u32)f32_to_bf16_rn(xv.w * av.w) << 16);
        *reinterpret_cast<uint2*>(&xpl[idx * 4]) = make_uint2(lo, hi);
    }
    const float4 z4 = make_float4(0.f, 0.f, 0.f, 0.f);
    #pragma unroll
    for (int k = 0; k < 4; ++k) acc4[t + 256 * k] = z4;
    __syncthreads();

    const u32* el = ecomb + b * NHW + t * 64;   // 256B-aligned
    float s   = 0.f;
    int   cur = (int)(el[0] >> 16);

    #define BF16V(E) __uint_as_float((u32)xpl[(E) & 0xFFFFu] << 16)
    #define ACCUM(E, V)                                            \
        {                                                          \
            const int cl_ = (int)((E) >> 16);                      \
            if (cl_ != cur) { atomicAdd(&acc[cur], s); s = 0.f; cur = cl_; } \
            s += (V);                                              \
        }

    for (int ch = 0; ch < 8; ++ch) {
        const uint4 e0 = *reinterpret_cast<const uint4*>(el + ch * 8);
        const uint4 e1 = *reinterpret_cast<const uint4*>(el + ch * 8 + 4);
        const float v0 = BF16V(e0.x);
        const float v1 = BF16V(e0.y);
        const float v2 = BF16V(e0.z);
        const float v3 = BF16V(e0.w);
        const float v4 = BF16V(e1.x);
        const float v5 = BF16V(e1.y);
        const float v6 = BF16V(e1.z);
        const float v7 = BF16V(e1.w);
        ACCUM(e0.x, v0); ACCUM(e0.y, v1); ACCUM(e0.z, v2); ACCUM(e0.w, v3);
        ACCUM(e1.x, v4); ACCUM(e1.y, v5); ACCUM(e1.z, v6); ACCUM(e1.w, v7);
    }
    atomicAdd(&acc[cur], s);
    #undef ACCUM
    #undef BF16V
    __syncthreads();

    const float4* as4 = reinterpret_cast<const float4*>(asum + b * NCELLS);
    float4* ob4 = reinterpret_cast<float4*>(out + (size_t)(b * NC + c) * NCELLS);
    #pragma unroll
    for (int k = 0; k < 4; ++k) {
        float4 a = acc4[t + 256 * k];
        const float4 sv = as4[t + 256 * k];
        a.x /= (sv.x + EPSF);
        a.y /= (sv.y + EPSF);
        a.z /= (sv.z + EPSF);
        a.w /= (sv.w + EPSF);
        ob4[t + 256 * k] = a;
    }
}

extern "C" void kernel_launch(void* const* d_in, const int* in_sizes, int n_in,
                              void* d_out, int out_size, void* d_ws, size_t ws_size,
                              hipStream_t stream)
{
    (void)in_sizes; (void)n_in; (void)out_size; (void)ws_size;
    const float* x  = (const float*)d_in[0];
    const float* cw = (const float*)d_in[1];
    const float* cb = (const float*)d_in[2];
    float* out = (float*)d_out;
    char*  ws  = (char*)d_ws;

    u16*   cells = (u16*)  (ws + WS_CELLS);
    float* atts  = (float*)(ws + WS_ATTS);
    u32*   ecomb = (u32*)  (ws + WS_ECOMB);
    float* asum  = (float*)(ws + WS_ASUM);

    k_conv  <<<dim3(NB * 256), dim3(256),  0, stream>>>(x, cw, cb, out, cells, atts);
    k_sort  <<<dim3(NB),       dim3(1024), 0, stream>>>(cells, atts, ecomb, asum);
    k_gather<<<dim3(NB * NC),  dim3(256),  0, stream>>>(x, atts, ecomb, asum, out);
}